// Round 6
// baseline (1049.347 us; speedup 1.0000x reference)
//
#include <hip/hip_runtime.h>
#include <hip/hip_bf16.h>
#include <stdint.h>

// Problem constants (QKVParallelLinearWithLoRA)
#define S_TOK 16384
#define DIN   4096
#define OUTQ  4096
#define OUTKV 1024
#define NOUT  6144   // OUTQ + 2*OUTKV
#define LRANK 64

typedef __attribute__((ext_vector_type(8))) short bf16x8;           // 8 bf16 = 4 VGPR
typedef __attribute__((ext_vector_type(4))) float f32x4;            // MFMA acc frag
typedef __attribute__((ext_vector_type(4))) unsigned short u16x4;   // 4 bf16 store

static __device__ __forceinline__ unsigned short f2bf(float f) {
  uint32_t u = __float_as_uint(f);
  u += 0x7FFFu + ((u >> 16) & 1u);
  return (unsigned short)(u >> 16);
}

static __device__ __forceinline__ void gload_lds16(const void* g, void* l) {
  __builtin_amdgcn_global_load_lds((const __attribute__((address_space(1))) void*)g,
                                   (__attribute__((address_space(3))) void*)l,
                                   16, 0, 0);
}

// ---------------------------------------------------------------------------
// Kernel 1: x fp32 -> bf16
// ---------------------------------------------------------------------------
__global__ __launch_bounds__(256) void cvt_f32_bf16(const float* __restrict__ in,
                                                    unsigned short* __restrict__ out,
                                                    int n4) {
  int i = blockIdx.x * blockDim.x + threadIdx.x;
  const int stride = gridDim.x * blockDim.x;
  const float4* in4 = (const float4*)in;
  for (; i < n4; i += stride) {
    float4 v = in4[i];
    u16x4 o;
    o.x = f2bf(v.x); o.y = f2bf(v.y); o.z = f2bf(v.z); o.w = f2bf(v.w);
    *(u16x4*)(out + (size_t)i * 4) = o;
  }
}

// ---------------------------------------------------------------------------
// Kernel 2: W_eff[o][d] = W[o][d] + sum_r B_seg[o'][r] * A[seg*64+r][d] -> bf16
// ---------------------------------------------------------------------------
__global__ __launch_bounds__(256) void prep_weff(const float* __restrict__ W,
                                                 const float* __restrict__ A,
                                                 const float* __restrict__ Bq,
                                                 const float* __restrict__ Bk,
                                                 const float* __restrict__ Bv,
                                                 unsigned short* __restrict__ Weff) {
  __shared__ float As_[64][128];
  __shared__ float Bs_[64][64];
  const int o0 = blockIdx.x * 64;
  const int d0 = blockIdx.y * 128;
  const int t = threadIdx.x;

  const float* Bseg; int seg, ob;
  if (o0 < OUTQ)              { seg = 0; Bseg = Bq; ob = o0; }
  else if (o0 < OUTQ + OUTKV) { seg = 1; Bseg = Bk; ob = o0 - OUTQ; }
  else                        { seg = 2; Bseg = Bv; ob = o0 - OUTQ - OUTKV; }

  {
    const float4* src = (const float4*)(Bseg + (size_t)ob * LRANK);
    float4* dst = (float4*)&Bs_[0][0];
    for (int i = t; i < 64 * 64 / 4; i += 256) dst[i] = src[i];
  }
  for (int i = t; i < 64 * 32; i += 256) {
    int r = i >> 5, c4 = i & 31;
    *(float4*)&As_[r][c4 * 4] =
        *(const float4*)(A + (size_t)(seg * 64 + r) * DIN + d0 + c4 * 4);
  }
  __syncthreads();

  const int tx = t & 31;
  const int tg = t >> 5;
  for (int oi = tg * 8; oi < tg * 8 + 8; ++oi) {
    const int o = o0 + oi;
    float4 acc = *(const float4*)(W + (size_t)o * DIN + d0 + tx * 4);
#pragma unroll 8
    for (int r = 0; r < 64; ++r) {
      const float b = Bs_[oi][r];
      const float4 a = *(const float4*)&As_[r][tx * 4];
      acc.x += b * a.x; acc.y += b * a.y; acc.z += b * a.z; acc.w += b * a.w;
    }
    u16x4 ov;
    ov.x = f2bf(acc.x); ov.y = f2bf(acc.y); ov.z = f2bf(acc.z); ov.w = f2bf(acc.w);
    *(u16x4*)(Weff + (size_t)o * DIN + d0 + tx * 4) = ov;
  }
}

// ---------------------------------------------------------------------------
// Kernel 3: 256x128 GEMM, BK=32, dbuf, counted vmcnt -- TWO BLOCKS PER CU.
//   C[m,n] = sum_k Xb[m,k]*Wb[n,k] + bias[n]
// 4 waves (2M x 2N), wave tile 128x64 (8x4 frags of 16x16x32 bf16 MFMA,
// acc = 128 AGPR). LDS 48KB/block (A 2x16KB + B 2x8KB) and ~210 regs/wave ->
// 2 independent blocks co-resident per CU (2 waves/SIMD from DIFFERENT
// barrier domains). Rationale (R4/R5 post-mortem): within one barrier domain
// the DS window (~2260 cyc/K64/CU) and MFMA window (2484 cyc/K64/SIMD)
// serialize regardless of per-wave software pipelining (R5 null). Two
// unsynced blocks overlap them at the CU scheduler level (m114 mechanism),
// with the m97 vmcnt(0)-drain disease fixed by counted vmcnt(6).
// Per K-tile: issue 6 gload_lds for T+1 -> vmcnt(6) [never 0 in main loop]
// -> barrier -> 12 ds_reads (compiler-scheduled lgkm waits) -> 32 MFMA
// (setprio-wrapped) -> barrier. Swizzle identical to R4 (0 conflicts).
// ---------------------------------------------------------------------------
__global__ __launch_bounds__(256, 2) void gemm_bt_bias(const unsigned short* __restrict__ Xb,
                                                       const unsigned short* __restrict__ Wb,
                                                       const float* __restrict__ bias,
                                                       float* __restrict__ C) {
  __shared__ unsigned short Alds[2][8192];  // [buf][256 rows][32 k] 16KB each
  __shared__ unsigned short Blds[2][4096];  // [buf][128 rows][32 k] 8KB each

  // bijective XCD co-residency swizzle: per XCD, the 64 concurrent blocks
  // (2/CU x 32 CU) tile an 8mt x 8nt rectangle; generations g sweep nt.
  // Per-tile staging working set per XCD: 8x256 A rows + 8x128 B rows = 192KB
  // (L2-fit, 8x reuse per fetch).
  const int bid = blockIdx.x;               // 0..3071, %8==0 grid
  const int x = bid & 7;                    // XCD
  const int l = bid >> 3;                   // 0..383
  const int g = l >> 6;                     // 0..5
  const int i6 = l & 63;
  const int mt = x * 8 + (i6 & 7);          // 0..63
  const int nt = g * 8 + (i6 >> 3);         // 0..47
  const int m0 = mt * 256;
  const int n0 = nt * 128;

  const int t = threadIdx.x;
  const int lane = t & 63;
  const int w = t >> 6;                     // 0..3
  const int wm = (w >> 1) * 128;            // 2 waves in M
  const int wn = (w & 1) * 64;              // 2 waves in N

  // staging: thread t covers row = i*64 + (t>>2) of each 64-row chunk, phys
  // 16B slot t&3; logical k-slot = (t&3)^((trow>>1)&3) (inverse swizzle on
  // the GLOBAL source; gload_lds LDS dest stays linear -- rule #21).
  const int trow = t >> 2;
  const int ksl = (t & 3) ^ ((trow >> 1) & 3);
  const size_t a0 = (size_t)(m0 + trow) * DIN + ksl * 8;
  const size_t b0 = (size_t)(n0 + trow) * DIN + ksl * 8;
  const int ldst = t * 8;                   // element offset within 64-row chunk

#define STAGE(T) do {                                                         \
    const int buf_ = (T) & 1;                                                 \
    const size_t ko_ = (size_t)(T) * 32;                                      \
    gload_lds16(Xb + a0 + 0 * 64 * DIN + ko_, &Alds[buf_][0 * 2048 + ldst]);  \
    gload_lds16(Xb + a0 + 1 * 64 * DIN + ko_, &Alds[buf_][1 * 2048 + ldst]);  \
    gload_lds16(Xb + a0 + 2 * 64 * DIN + ko_, &Alds[buf_][2 * 2048 + ldst]);  \
    gload_lds16(Xb + a0 + 3 * 64 * DIN + ko_, &Alds[buf_][3 * 2048 + ldst]);  \
    gload_lds16(Wb + b0 + 0 * 64 * DIN + ko_, &Blds[buf_][0 * 2048 + ldst]);  \
    gload_lds16(Wb + b0 + 1 * 64 * DIN + ko_, &Blds[buf_][1 * 2048 + ldst]);  \
  } while (0)

  // fragment read offsets (bytes): row = base + lr, 16B at (lane>>4)*16,
  // swizzle-xor reduces to a per-lane constant (row%8 == lr%8 since bases
  // are multiples of 16).
  const int lr = lane & 15;
  const int ks16 = (lane >> 4) * 16;
  const int fxor = ((lr >> 1) & 3) << 4;
  const int aoff = ((wm + lr) * 64 + ks16) ^ fxor;
  const int boff = ((wn + lr) * 64 + ks16) ^ fxor;

  f32x4 acc[8][4];
#pragma unroll
  for (int i = 0; i < 8; ++i)
#pragma unroll
    for (int j = 0; j < 4; ++j)
      acc[i][j] = f32x4{0.f, 0.f, 0.f, 0.f};

  // prologue: stage tile 0 (6 loads in flight)
  STAGE(0);

  for (int T = 0; T < 128; ++T) {
    const int buf = T & 1;
    if (T < 127) {
      STAGE(T + 1);                          // 6 new -> 12 outstanding
      asm volatile("s_waitcnt vmcnt(6)" ::: "memory");  // oldest 6 = tile T
    } else {
      asm volatile("s_waitcnt vmcnt(0)" ::: "memory");  // drain last tile
    }
    __builtin_amdgcn_s_barrier();            // all waves' tile-T data visible

    const char* Ar = (const char*)&Alds[buf][0];
    const char* Br = (const char*)&Blds[buf][0];
    bf16x8 af[8], bq[4];
#pragma unroll
    for (int mi = 0; mi < 8; ++mi)
      af[mi] = *(const bf16x8*)(Ar + aoff + mi * 1024);
#pragma unroll
    for (int ni = 0; ni < 4; ++ni)
      bq[ni] = *(const bf16x8*)(Br + boff + ni * 1024);

    __builtin_amdgcn_s_setprio(1);
#pragma unroll
    for (int mi = 0; mi < 8; ++mi)
#pragma unroll
      for (int ni = 0; ni < 4; ++ni)
        acc[mi][ni] = __builtin_amdgcn_mfma_f32_16x16x32_bf16(af[mi], bq[ni],
                                                              acc[mi][ni], 0, 0, 0);
    __builtin_amdgcn_s_setprio(0);
    __builtin_amdgcn_s_barrier();            // all reads of buf done before
                                             // next iter stages into buf^1's
                                             // sibling (WAR fence)
  }
#undef STAGE

  // epilogue: C/D layout col=lane&15, row=(lane>>4)*4+reg (m89/m91-verified)
  const int cr4 = (lane >> 4) * 4;
#pragma unroll
  for (int ni = 0; ni < 4; ++ni) {
    const int col = n0 + wn + ni * 16 + lr;
    const float bv = bias[col];
#pragma unroll
    for (int mi = 0; mi < 8; ++mi) {
      const int row = m0 + wm + mi * 16 + cr4;
#pragma unroll
      for (int jj = 0; jj < 4; ++jj)
        C[(size_t)(row + jj) * NOUT + col] = acc[mi][ni][jj] + bv;
    }
  }
}

// ---------------------------------------------------------------------------
extern "C" void kernel_launch(void* const* d_in, const int* in_sizes, int n_in,
                              void* d_out, int out_size, void* d_ws, size_t ws_size,
                              hipStream_t stream) {
  const float* x    = (const float*)d_in[0];
  const float* Wqkv = (const float*)d_in[1];
  const float* bias = (const float*)d_in[2];
  const float* Aq   = (const float*)d_in[3];
  const float* Bq   = (const float*)d_in[4];
  const float* Bk   = (const float*)d_in[5];
  const float* Bv   = (const float*)d_in[6];
  float* out = (float*)d_out;

  unsigned short* xb = (unsigned short*)d_ws;                 // 128 MB
  unsigned short* wb = xb + (size_t)S_TOK * DIN;              // 48 MB

  cvt_f32_bf16<<<2048, 256, 0, stream>>>(x, xb, S_TOK * DIN / 4);

  dim3 g1(NOUT / 64, DIN / 128);
  prep_weff<<<g1, 256, 0, stream>>>(Wqkv, Aq, Bq, Bk, Bv, wb);

  gemm_bt_bias<<<3072, 256, 0, stream>>>(xb, wb, bias, out);
}

// Round 7
// 979.269 us; speedup vs baseline: 1.0716x; 1.0716x over previous
//
#include <hip/hip_runtime.h>
#include <hip/hip_bf16.h>
#include <stdint.h>

// Problem constants (QKVParallelLinearWithLoRA)
#define S_TOK 16384
#define DIN   4096
#define OUTQ  4096
#define OUTKV 1024
#define NOUT  6144   // OUTQ + 2*OUTKV
#define LRANK 64

typedef __attribute__((ext_vector_type(8))) short bf16x8;           // 8 bf16 = 4 VGPR
typedef __attribute__((ext_vector_type(4))) float f32x4;
typedef __attribute__((ext_vector_type(16))) float f32x16;          // 32x32 MFMA acc
typedef __attribute__((ext_vector_type(4))) unsigned short u16x4;   // 4 bf16 store

static __device__ __forceinline__ unsigned short f2bf(float f) {
  uint32_t u = __float_as_uint(f);
  u += 0x7FFFu + ((u >> 16) & 1u);
  return (unsigned short)(u >> 16);
}

static __device__ __forceinline__ void gload_lds16(const void* g, void* l) {
  __builtin_amdgcn_global_load_lds((const __attribute__((address_space(1))) void*)g,
                                   (__attribute__((address_space(3))) void*)l,
                                   16, 0, 0);
}

// ---------------------------------------------------------------------------
// Kernel 1: x fp32 -> bf16
// ---------------------------------------------------------------------------
__global__ __launch_bounds__(256) void cvt_f32_bf16(const float* __restrict__ in,
                                                    unsigned short* __restrict__ out,
                                                    int n4) {
  int i = blockIdx.x * blockDim.x + threadIdx.x;
  const int stride = gridDim.x * blockDim.x;
  const float4* in4 = (const float4*)in;
  for (; i < n4; i += stride) {
    float4 v = in4[i];
    u16x4 o;
    o.x = f2bf(v.x); o.y = f2bf(v.y); o.z = f2bf(v.z); o.w = f2bf(v.w);
    *(u16x4*)(out + (size_t)i * 4) = o;
  }
}

// ---------------------------------------------------------------------------
// Kernel 2: W_eff[o][d] = W[o][d] + sum_r B_seg[o'][r] * A[seg*64+r][d] -> bf16
// ---------------------------------------------------------------------------
__global__ __launch_bounds__(256) void prep_weff(const float* __restrict__ W,
                                                 const float* __restrict__ A,
                                                 const float* __restrict__ Bq,
                                                 const float* __restrict__ Bk,
                                                 const float* __restrict__ Bv,
                                                 unsigned short* __restrict__ Weff) {
  __shared__ float As_[64][128];
  __shared__ float Bs_[64][64];
  const int o0 = blockIdx.x * 64;
  const int d0 = blockIdx.y * 128;
  const int t = threadIdx.x;

  const float* Bseg; int seg, ob;
  if (o0 < OUTQ)              { seg = 0; Bseg = Bq; ob = o0; }
  else if (o0 < OUTQ + OUTKV) { seg = 1; Bseg = Bk; ob = o0 - OUTQ; }
  else                        { seg = 2; Bseg = Bv; ob = o0 - OUTQ - OUTKV; }

  {
    const float4* src = (const float4*)(Bseg + (size_t)ob * LRANK);
    float4* dst = (float4*)&Bs_[0][0];
    for (int i = t; i < 64 * 64 / 4; i += 256) dst[i] = src[i];
  }
  for (int i = t; i < 64 * 32; i += 256) {
    int r = i >> 5, c4 = i & 31;
    *(float4*)&As_[r][c4 * 4] =
        *(const float4*)(A + (size_t)(seg * 64 + r) * DIN + d0 + c4 * 4);
  }
  __syncthreads();

  const int tx = t & 31;
  const int tg = t >> 5;
  for (int oi = tg * 8; oi < tg * 8 + 8; ++oi) {
    const int o = o0 + oi;
    float4 acc = *(const float4*)(W + (size_t)o * DIN + d0 + tx * 4);
#pragma unroll 8
    for (int r = 0; r < 64; ++r) {
      const float b = Bs_[oi][r];
      const float4 a = *(const float4*)&As_[r][tx * 4];
      acc.x += b * a.x; acc.y += b * a.y; acc.z += b * a.z; acc.w += b * a.w;
    }
    u16x4 ov;
    ov.x = f2bf(acc.x); ov.y = f2bf(acc.y); ov.z = f2bf(acc.z); ov.w = f2bf(acc.w);
    *(u16x4*)(Weff + (size_t)o * DIN + d0 + tx * 4) = ov;
  }
}

// ---------------------------------------------------------------------------
// Kernel 3: 256x256 GEMM, BK=64, 8-phase, 32x32x16 MFMA (2495 TF ceiling vs
// 2075 for 16x16x32 -- m119/m06), rotated stage schedule with vmcnt(4) only
// at P4/P8 (stage->read distance 4-6 phases).
//   C[m,n] = sum_k Xb[m,k]*Wb[n,k] + bias[n]
// 8 waves (2M x 4N), wave tile 128x64 = 4m x 2n frags of 32x32, acc f32x16[4][2]
// (128 regs). LDS identical to R4: A/B x [2 buf][2 kh][256 rows][32 k] = 128KB,
// swizzle byte ^= ((row>>1)&3)<<4 (measured 0 conflicts; 32-row frag reads
// partition into 8 full-bank cycles -- conflict-free by the same mechanism).
// Phase (kh, ks2): read 4 A-frags + 2 B-frags (6 ds_read_b128), 1 stage
// (2 gloads), barrier, lgkmcnt(0), setprio(1), 8 MFMA, setprio(0), end.
// Stage rotation per iter (Ta=2i buf0 p1-4, Tb=2i+1 buf1 p5-8):
//   p1:A(Tb,1) p2:B(Tb,1) p3:A(Ta+2,0) p4:B(Ta+2,0)+vmcnt(4)
//   p5:A(Ta+2,1) p6:B(Ta+2,1) p7:A(Tb+2,0) p8:B(Tb+2,0)+vmcnt(4)
// Ledger verified: at p4-end landed through p2 (covers Tb reads p5-8); at
// p8-end landed through p6 (covers Ta+2 reads next p1-4); carry = 4 loads.
// WAR: every slot staged >=1 phase after its last read, barrier between.
// Tail (Ta=62,Tb=63): stages only p1,p2; vmcnt(0) at p4; rest plain barriers.
// ---------------------------------------------------------------------------
__global__ __launch_bounds__(512, 1) void gemm_bt_bias(const unsigned short* __restrict__ Xb,
                                                       const unsigned short* __restrict__ Wb,
                                                       const float* __restrict__ bias,
                                                       float* __restrict__ C) {
  __shared__ unsigned short Alds[32768];  // [buf][kh][256 rows][32 k] = 4x16KB
  __shared__ unsigned short Blds[32768];

  // 2-D co-residency swizzle (R4: FETCH 3.2x lower): XCD x owns mt-band
  // [8x,8x+8); 32 concurrent slots tile 8mt x 4nt; generations sweep nt.
  const int bid = blockIdx.x;
  const int x = bid & 7;
  const int l = bid >> 3;
  const int g = l >> 5;
  const int i5 = l & 31;
  const int mt = x * 8 + (i5 & 7);
  const int nt = g * 4 + (i5 >> 3);
  const int m0 = mt * 256;
  const int n0 = nt * 256;

  const int t = threadIdx.x;
  const int lane = t & 63;
  const int w = t >> 6;
  const int wm = (w >> 2) * 128;          // 2 waves in M
  const int wn = (w & 3) * 64;            // 4 waves in N

  // staging (identical to R4): thread t -> region row t>>2 (+128 for 2nd
  // gload), phys 16B-slot t&3; logical k-slot = (t&3)^((trow>>1)&3).
  const int trow = t >> 2;
  const int ksl = (t & 3) ^ ((trow >> 1) & 3);
  const size_t gA0 = (size_t)(m0 + trow) * DIN + ksl * 8;
  const size_t gA1 = (size_t)(m0 + 128 + trow) * DIN + ksl * 8;
  const size_t gB0 = (size_t)(n0 + trow) * DIN + ksl * 8;
  const size_t gB1 = (size_t)(n0 + 128 + trow) * DIN + ksl * 8;
  const int ldst = t * 8;

#define STAGE_A(T, kh) do {                                                   \
    const int rb_ = (((T) & 1) * 2 + (kh)) * 8192;                            \
    const size_t ko_ = (size_t)((T) * 64 + (kh) * 32);                        \
    gload_lds16(Xb + gA0 + ko_, &Alds[rb_ + ldst]);                           \
    gload_lds16(Xb + gA1 + ko_, &Alds[rb_ + 4096 + ldst]);                    \
  } while (0)
#define STAGE_B(T, kh) do {                                                   \
    const int rb_ = (((T) & 1) * 2 + (kh)) * 8192;                            \
    const size_t ko_ = (size_t)((T) * 64 + (kh) * 32);                        \
    gload_lds16(Wb + gB0 + ko_, &Blds[rb_ + ldst]);                           \
    gload_lds16(Wb + gB1 + ko_, &Blds[rb_ + 4096 + ldst]);                    \
  } while (0)

  // 32x32 fragment read constants. Frag (mi, ks2): lane reads
  // row = base + mi*32 + (lane&31), bytes [ks2*32 + (lane>>5)*16, +16)
  // within the 64B row, XOR-swizzled by ((row>>1)&3)<<4 (lane-constant).
  const int lr32 = lane & 31;
  const int hi = lane >> 5;
  const int fx32 = ((lr32 >> 1) & 3) << 4;
  const int kx0 = (hi * 16) ^ fx32;         // ks2 = 0
  const int kx1 = (32 + hi * 16) ^ fx32;    // ks2 = 1
  const int aA = (wm + lr32) * 64;          // byte offset of row in region
  const int bB = (wn + lr32) * 64;

  f32x16 acc[4][2];
#pragma unroll
  for (int i = 0; i < 4; ++i)
#pragma unroll
    for (int j = 0; j < 2; ++j)
      acc[i][j] = (f32x16)(0.f);

#define END_P()  __builtin_amdgcn_s_barrier()
#define END_V4() do { asm volatile("s_waitcnt vmcnt(4)" ::: "memory");        \
                      __builtin_amdgcn_s_barrier(); } while (0)
#define END_V0() do { asm volatile("s_waitcnt vmcnt(0)" ::: "memory");        \
                      __builtin_amdgcn_s_barrier(); } while (0)

  // One phase: 6 ds_read_b128, 1 stage, barrier, lgkm0, 8 x mfma 32x32x16.
#define PH32(buf, kh, ks2, STAGE_STMT, ENDM) do {                             \
    const char* Ar_ = (const char*)Alds + ((buf) * 2 + (kh)) * 16384;         \
    const char* Br_ = (const char*)Blds + ((buf) * 2 + (kh)) * 16384;         \
    const int kx_ = (ks2) ? kx1 : kx0;                                        \
    bf16x8 af_[4], bq_[2];                                                    \
    _Pragma("unroll")                                                         \
    for (int mi_ = 0; mi_ < 4; ++mi_)                                         \
      af_[mi_] = *(const bf16x8*)(Ar_ + aA + mi_ * 2048 + kx_);               \
    _Pragma("unroll")                                                         \
    for (int ni_ = 0; ni_ < 2; ++ni_)                                         \
      bq_[ni_] = *(const bf16x8*)(Br_ + bB + ni_ * 2048 + kx_);               \
    STAGE_STMT;                                                               \
    __builtin_amdgcn_s_barrier();                                             \
    asm volatile("s_waitcnt lgkmcnt(0)" ::: "memory");                        \
    __builtin_amdgcn_s_setprio(1);                                            \
    _Pragma("unroll")                                                         \
    for (int mi_ = 0; mi_ < 4; ++mi_)                                         \
      _Pragma("unroll")                                                       \
      for (int ni_ = 0; ni_ < 2; ++ni_)                                       \
        acc[mi_][ni_] = __builtin_amdgcn_mfma_f32_32x32x16_bf16(              \
            af_[mi_], bq_[ni_], acc[mi_][ni_], 0, 0, 0);                      \
    __builtin_amdgcn_s_setprio(0);                                            \
    ENDM();                                                                   \
  } while (0)

  // prologue: tile0 fully + tile1 kh0; vmcnt(4) -> tile0's 8 loads landed,
  // carry = {A(1,0), B(1,0)} (checked at first P4).
  STAGE_A(0, 0); STAGE_B(0, 0); STAGE_A(0, 1); STAGE_B(0, 1);
  STAGE_A(1, 0); STAGE_B(1, 0);
  asm volatile("s_waitcnt vmcnt(4)" ::: "memory");
  __builtin_amdgcn_s_barrier();

  for (int i = 0; i < 31; ++i) {
    const int Tb = 2 * i + 1, Tc = 2 * i + 2, Td = 2 * i + 3;
    PH32(0, 0, 0, STAGE_A(Tb, 1), END_P);   // p1
    PH32(0, 0, 1, STAGE_B(Tb, 1), END_P);   // p2
    PH32(0, 1, 0, STAGE_A(Tc, 0), END_P);   // p3
    PH32(0, 1, 1, STAGE_B(Tc, 0), END_V4);  // p4: Tb fully landed
    PH32(1, 0, 0, STAGE_A(Tc, 1), END_P);   // p5
    PH32(1, 0, 1, STAGE_B(Tc, 1), END_P);   // p6
    PH32(1, 1, 0, STAGE_A(Td, 0), END_P);   // p7
    PH32(1, 1, 1, STAGE_B(Td, 0), END_V4);  // p8: Tc fully landed
  }
  // tail: Ta=62 (buf0), Tb=63 (buf1); stage only 63's kh1; drain at p4.
  PH32(0, 0, 0, STAGE_A(63, 1), END_P);
  PH32(0, 0, 1, STAGE_B(63, 1), END_P);
  PH32(0, 1, 0, ((void)0), END_P);
  PH32(0, 1, 1, ((void)0), END_V0);         // all of tile 63 landed
  PH32(1, 0, 0, ((void)0), END_P);
  PH32(1, 0, 1, ((void)0), END_P);
  PH32(1, 1, 0, ((void)0), END_P);
  PH32(1, 1, 1, ((void)0), END_P);

#undef PH32
#undef STAGE_A
#undef STAGE_B
#undef END_P
#undef END_V4
#undef END_V0

  // epilogue: 32x32 C/D layout (m74/m101-verified):
  // col = lane&31, row = (reg&3) + 8*(reg>>2) + 4*(lane>>5)
#pragma unroll
  for (int ni = 0; ni < 2; ++ni) {
    const int col = n0 + wn + ni * 32 + lr32;
    const float bv = bias[col];
#pragma unroll
    for (int mi = 0; mi < 4; ++mi) {
      const int rbase = m0 + wm + mi * 32 + 4 * hi;
#pragma unroll
      for (int r = 0; r < 16; ++r) {
        const int row = rbase + (r & 3) + 8 * (r >> 2);
        C[(size_t)row * NOUT + col] = acc[mi][ni][r] + bv;
      }
    }
  }
}

// ---------------------------------------------------------------------------
extern "C" void kernel_launch(void* const* d_in, const int* in_sizes, int n_in,
                              void* d_out, int out_size, void* d_ws, size_t ws_size,
                              hipStream_t stream) {
  const float* x    = (const float*)d_in[0];
  const float* Wqkv = (const float*)d_in[1];
  const float* bias = (const float*)d_in[2];
  const float* Aq   = (const float*)d_in[3];
  const float* Bq   = (const float*)d_in[4];
  const float* Bk   = (const float*)d_in[5];
  const float* Bv   = (const float*)d_in[6];
  float* out = (float*)d_out;

  unsigned short* xb = (unsigned short*)d_ws;                 // 128 MB
  unsigned short* wb = xb + (size_t)S_TOK * DIN;              // 48 MB

  cvt_f32_bf16<<<2048, 256, 0, stream>>>(x, xb, S_TOK * DIN / 4);

  dim3 g1(NOUT / 64, DIN / 128);
  prep_weff<<<g1, 256, 0, stream>>>(Wqkv, Aq, Bq, Bk, Bv, wb);

  gemm_bt_bias<<<1536, 512, 0, stream>>>(xb, wb, bias, out);
}